// Round 1
// baseline (2502.664 us; speedup 1.0000x reference)
//
#include <hip/hip_runtime.h>

#define N_ROWS 131072
#define DIM 64
#define K_CODES 4096

// ---- Kernel 1: e2[k] = sum_d embed[k][d]^2 ----
__global__ void e2_kernel(const float* __restrict__ embed, float* __restrict__ e2) {
    int k = blockIdx.x * blockDim.x + threadIdx.x;
    if (k >= K_CODES) return;
    const float4* e = reinterpret_cast<const float4*>(embed + (size_t)k * DIM);
    float s = 0.f;
#pragma unroll
    for (int i = 0; i < DIM / 4; ++i) {
        float4 v = e[i];
        s = fmaf(v.x, v.x, s);
        s = fmaf(v.y, v.y, s);
        s = fmaf(v.z, v.z, s);
        s = fmaf(v.w, v.w, s);
    }
    e2[k] = s;
}

// ---- Kernel 2: per-row argmin over K codes ----
// One thread = one x row (64 floats in VGPRs). embed/e2 reads are wave-uniform
// -> compiler promotes to s_load; inner loop is v_fmac_f32 v,s,v (pure VALU).
__global__ __launch_bounds__(256) void argmin_kernel(
        const float* __restrict__ x, const float* __restrict__ embed,
        const float* __restrict__ e2, int* __restrict__ ind_ws,
        float* __restrict__ ind_out) {
    const int row = blockIdx.x * blockDim.x + threadIdx.x;

    float xr[DIM];
    const float4* xp = reinterpret_cast<const float4*>(x + (size_t)row * DIM);
#pragma unroll
    for (int i = 0; i < DIM / 4; ++i) {
        float4 v = xp[i];
        xr[i * 4 + 0] = v.x;
        xr[i * 4 + 1] = v.y;
        xr[i * 4 + 2] = v.z;
        xr[i * 4 + 3] = v.w;
    }

    float best = 3.4e38f;
    int bi = 0;
    for (int k = 0; k < K_CODES; ++k) {
        const float* e = embed + (size_t)k * DIM;  // wave-uniform address
        float d0 = 0.f, d1 = 0.f, d2 = 0.f, d3 = 0.f;
#pragma unroll
        for (int i = 0; i < DIM; i += 4) {
            d0 = fmaf(xr[i + 0], e[i + 0], d0);
            d1 = fmaf(xr[i + 1], e[i + 1], d1);
            d2 = fmaf(xr[i + 2], e[i + 2], d2);
            d3 = fmaf(xr[i + 3], e[i + 3], d3);
        }
        float dot = (d0 + d1) + (d2 + d3);
        float score = fmaf(-2.f, dot, e2[k]);  // ||x||^2 const per row: dropped
        if (score < best) { best = score; bi = k; }  // strict < keeps first min
    }
    ind_ws[row] = bi;
    ind_out[row] = (float)bi;  // whole d_out buffer is read back as float32
}

// ---- Kernel 3: gather quantize + scatter stats ----
// One wave (64 lanes) = one row; lane d handles element d.
__global__ void scatter_kernel(const float* __restrict__ x,
                               const float* __restrict__ embed,
                               const int* __restrict__ ind,
                               float* __restrict__ quant,
                               float* __restrict__ cs,
                               float* __restrict__ es) {
    const int t = blockIdx.x * blockDim.x + threadIdx.x;  // over N*DIM
    const int row = t >> 6;
    const int d = t & 63;
    const int k = ind[row];                    // broadcast within wave
    quant[t] = embed[(size_t)k * DIM + d];     // coalesced gather
    atomicAdd(&es[(size_t)k * DIM + d], x[t]); // fp32 device-scope atomic
    if (d == 0) atomicAdd(&cs[k], 1.0f);       // one atomic per wave
}

extern "C" void kernel_launch(void* const* d_in, const int* in_sizes, int n_in,
                              void* d_out, int out_size, void* d_ws, size_t ws_size,
                              hipStream_t stream) {
    const float* x     = (const float*)d_in[0];
    const float* embed = (const float*)d_in[1];

    float* out      = (float*)d_out;
    float* quant    = out;                                  // [N, D]
    float* ind_out  = out + (size_t)N_ROWS * DIM;           // [N] (as float)
    float* cs       = ind_out + N_ROWS;                     // [K]
    float* es       = cs + K_CODES;                         // [K, D]

    float* e2     = (float*)d_ws;                           // [K]
    int*   ind_ws = (int*)((char*)d_ws + K_CODES * sizeof(float));  // [N]

    // Stats are accumulated with atomics; d_out is poisoned 0xAA before each run.
    hipMemsetAsync(cs, 0, (size_t)(K_CODES + K_CODES * DIM) * sizeof(float), stream);

    e2_kernel<<<K_CODES / 256, 256, 0, stream>>>(embed, e2);
    argmin_kernel<<<N_ROWS / 256, 256, 0, stream>>>(x, embed, e2, ind_ws, ind_out);
    scatter_kernel<<<(size_t)N_ROWS * DIM / 256, 256, 0, stream>>>(
        x, embed, ind_ws, quant, cs, es);
}

// Round 2
// 1200.671 us; speedup vs baseline: 2.0844x; 2.0844x over previous
//
#include <hip/hip_runtime.h>

#define N_ROWS 131072
#define DIM 64
#define K_CODES 4096
#define KSPLIT 4
#define KCHUNK (K_CODES / KSPLIT)  // 1024 codes per split

// ---- Kernel 1: e2[k] = sum_d embed[k][d]^2 ----
__global__ void e2_kernel(const float* __restrict__ embed, float* __restrict__ e2) {
    int k = blockIdx.x * blockDim.x + threadIdx.x;
    if (k >= K_CODES) return;
    const float4* e = reinterpret_cast<const float4*>(embed + (size_t)k * DIM);
    float s = 0.f;
#pragma unroll
    for (int i = 0; i < DIM / 4; ++i) {
        float4 v = e[i];
        s = fmaf(v.x, v.x, s);
        s = fmaf(v.y, v.y, s);
        s = fmaf(v.z, v.z, s);
        s = fmaf(v.w, v.w, s);
    }
    e2[k] = s;
}

// ---- Kernel 2: partial argmin. grid = (N/256, KSPLIT). ----
// Thread (row, s) scans codes [s*KCHUNK, (s+1)*KCHUNK). Row held in VGPRs
// (launch_bounds(256,4) -> 128-VGPR cap, ~80 used -> 6 waves/SIMD; grid
// supplies 32 waves/CU so occupancy is VGPR-capped at ~24/CU, not grid-capped).
// embed/e2 addresses are wave-uniform -> s_load; inner loop is v_fmac v,s,v.
__global__ __launch_bounds__(256, 4) void argmin_part_kernel(
        const float* __restrict__ x, const float* __restrict__ embed,
        const float* __restrict__ e2,
        float* __restrict__ best_ws, int* __restrict__ idx_ws) {
    const int row = blockIdx.x * blockDim.x + threadIdx.x;
    const int s = blockIdx.y;
    const int k0 = s * KCHUNK;

    float xr[DIM];
    const float4* xp = reinterpret_cast<const float4*>(x + (size_t)row * DIM);
#pragma unroll
    for (int i = 0; i < DIM / 4; ++i) {
        float4 v = xp[i];
        xr[i * 4 + 0] = v.x;
        xr[i * 4 + 1] = v.y;
        xr[i * 4 + 2] = v.z;
        xr[i * 4 + 3] = v.w;
    }

    float best = 3.4e38f;
    int bi = k0;
    for (int k = k0; k < k0 + KCHUNK; ++k) {
        const float* e = embed + (size_t)k * DIM;  // wave-uniform
        float d0 = 0.f, d1 = 0.f, d2 = 0.f, d3 = 0.f;
#pragma unroll
        for (int i = 0; i < DIM; i += 4) {
            d0 = fmaf(xr[i + 0], e[i + 0], d0);
            d1 = fmaf(xr[i + 1], e[i + 1], d1);
            d2 = fmaf(xr[i + 2], e[i + 2], d2);
            d3 = fmaf(xr[i + 3], e[i + 3], d3);
        }
        float dot = (d0 + d1) + (d2 + d3);
        float score = fmaf(-2.f, dot, e2[k]);
        if (score < best) { best = score; bi = k; }  // strict < keeps lowest k
    }
    best_ws[(size_t)s * N_ROWS + row] = best;
    idx_ws[(size_t)s * N_ROWS + row] = bi;
}

// ---- Kernel 3: merge KSPLIT partial argmins per row ----
__global__ void argmin_merge_kernel(const float* __restrict__ best_ws,
                                    const int* __restrict__ idx_ws,
                                    int* __restrict__ ind_ws,
                                    float* __restrict__ ind_out) {
    const int row = blockIdx.x * blockDim.x + threadIdx.x;
    float b = best_ws[row];
    int bi = idx_ws[row];
#pragma unroll
    for (int s = 1; s < KSPLIT; ++s) {
        float v = best_ws[(size_t)s * N_ROWS + row];
        int vi = idx_ws[(size_t)s * N_ROWS + row];
        // strict <: on exact ties keep the earlier split = lower index,
        // matching argmin-first semantics (identical FMA order per k).
        if (v < b) { b = v; bi = vi; }
    }
    ind_ws[row] = bi;
    ind_out[row] = (float)bi;
}

// ---- Kernel 4: gather quantize + scatter stats (one wave = one row) ----
__global__ void scatter_kernel(const float* __restrict__ x,
                               const float* __restrict__ embed,
                               const int* __restrict__ ind,
                               float* __restrict__ quant,
                               float* __restrict__ cs,
                               float* __restrict__ es) {
    const int t = blockIdx.x * blockDim.x + threadIdx.x;  // over N*DIM
    const int row = t >> 6;
    const int d = t & 63;
    const int k = ind[row];                    // broadcast within wave
    quant[t] = embed[(size_t)k * DIM + d];     // coalesced gather
    atomicAdd(&es[(size_t)k * DIM + d], x[t]); // fp32 device-scope atomic
    if (d == 0) atomicAdd(&cs[k], 1.0f);       // one atomic per wave
}

extern "C" void kernel_launch(void* const* d_in, const int* in_sizes, int n_in,
                              void* d_out, int out_size, void* d_ws, size_t ws_size,
                              hipStream_t stream) {
    const float* x     = (const float*)d_in[0];
    const float* embed = (const float*)d_in[1];

    float* out      = (float*)d_out;
    float* quant    = out;                                  // [N, D]
    float* ind_out  = out + (size_t)N_ROWS * DIM;           // [N] (as float)
    float* cs       = ind_out + N_ROWS;                     // [K]
    float* es       = cs + K_CODES;                         // [K, D]

    // ws layout: e2 [K] | best_ws [KSPLIT*N] | idx_ws [KSPLIT*N] | ind_ws [N]
    float* e2      = (float*)d_ws;
    float* best_ws = e2 + K_CODES;
    int*   idx_ws  = (int*)(best_ws + (size_t)KSPLIT * N_ROWS);
    int*   ind_ws  = idx_ws + (size_t)KSPLIT * N_ROWS;

    hipMemsetAsync(cs, 0, (size_t)(K_CODES + K_CODES * DIM) * sizeof(float), stream);

    e2_kernel<<<K_CODES / 256, 256, 0, stream>>>(embed, e2);
    argmin_part_kernel<<<dim3(N_ROWS / 256, KSPLIT), 256, 0, stream>>>(
        x, embed, e2, best_ws, idx_ws);
    argmin_merge_kernel<<<N_ROWS / 256, 256, 0, stream>>>(
        best_ws, idx_ws, ind_ws, ind_out);
    scatter_kernel<<<(size_t)N_ROWS * DIM / 256, 256, 0, stream>>>(
        x, embed, ind_ws, quant, cs, es);
}

// Round 3
// 1088.152 us; speedup vs baseline: 2.2999x; 1.1034x over previous
//
#include <hip/hip_runtime.h>

#define N_ROWS 131072
#define DIM 64
#define K_CODES 4096

#define BM 128          // rows per block tile
#define BN 128          // codes per block tile
#define DHALF 32        // d-chunk staged per phase
#define ST 36           // LDS row stride (32 data + 4 pad): 16B-aligned rows,
                        // frag-read banks spread (x: 4 distinct, e: 2-way = free)

// order-preserving float -> uint32 (min over keys == min over floats)
__device__ inline unsigned int fkey(float f) {
    unsigned int u = __float_as_uint(f);
    return (u & 0x80000000u) ? ~u : (u | 0x80000000u);
}

// ---- e2[k] = sum_d embed[k][d]^2 ----
__global__ void e2_kernel(const float* __restrict__ embed, float* __restrict__ e2) {
    int k = blockIdx.x * blockDim.x + threadIdx.x;
    const float4* e = reinterpret_cast<const float4*>(embed + (size_t)k * DIM);
    float s = 0.f;
#pragma unroll
    for (int i = 0; i < DIM / 4; ++i) {
        float4 v = e[i];
        s = fmaf(v.x, v.x, s);
        s = fmaf(v.y, v.y, s);
        s = fmaf(v.z, v.z, s);
        s = fmaf(v.w, v.w, s);
    }
    e2[k] = s;
}

// ---- tiled distance + fused argmin ----
// grid = (32768): 128x128 tile per block, 8x8 per thread, d staged in 2 halves.
__global__ __launch_bounds__(256, 4) void dist_argmin_kernel(
        const float* __restrict__ x, const float* __restrict__ embed,
        const float* __restrict__ e2, unsigned long long* __restrict__ packed) {
    __shared__ __align__(16) float smem[2 * BM * ST];  // 36864 B
    float* xs = smem;
    float* es = smem + BM * ST;

    const int r0 = blockIdx.x * BM;   // row-tile fastest -> e tile stays L2-hot
    const int c0 = blockIdx.y * BN;
    const int tx = threadIdx.x & 15;
    const int ty = threadIdx.x >> 4;

    float acc[8][8];
#pragma unroll
    for (int i = 0; i < 8; ++i)
#pragma unroll
        for (int j = 0; j < 8; ++j) acc[i][j] = 0.f;

#pragma unroll
    for (int half = 0; half < 2; ++half) {
        const int d0 = half * DHALF;
        // stage x[r0:+128][d0:+32] and embed[c0:+128][d0:+32]; 4 float4 each
#pragma unroll
        for (int p = 0; p < 4; ++p) {
            int t = threadIdx.x + p * 256;   // 0..1023
            int row = t >> 3;
            int q = (t & 7) * 4;
            float4 xv = *(const float4*)(x + (size_t)(r0 + row) * DIM + d0 + q);
            *(float4*)(&xs[row * ST + q]) = xv;
            float4 ev = *(const float4*)(embed + (size_t)(c0 + row) * DIM + d0 + q);
            *(float4*)(&es[row * ST + q]) = ev;
        }
        __syncthreads();

        for (int dd = 0; dd < DHALF; dd += 4) {
            float4 xf[8];
#pragma unroll
            for (int i = 0; i < 8; ++i)
                xf[i] = *(const float4*)(&xs[(ty + 16 * i) * ST + dd]);
#pragma unroll
            for (int jj = 0; jj < 8; jj += 4) {
                float4 ef[4];
#pragma unroll
                for (int j = 0; j < 4; ++j)
                    ef[j] = *(const float4*)(&es[(tx + 16 * (jj + j)) * ST + dd]);
#pragma unroll
                for (int i = 0; i < 8; ++i)
#pragma unroll
                    for (int j = 0; j < 4; ++j) {
                        acc[i][jj + j] = fmaf(xf[i].x, ef[j].x, acc[i][jj + j]);
                        acc[i][jj + j] = fmaf(xf[i].y, ef[j].y, acc[i][jj + j]);
                        acc[i][jj + j] = fmaf(xf[i].z, ef[j].z, acc[i][jj + j]);
                        acc[i][jj + j] = fmaf(xf[i].w, ef[j].w, acc[i][jj + j]);
                    }
            }
        }
        __syncthreads();
    }

    // per-thread argmin over its 8 cols, per row
    unsigned long long mykey[8];
#pragma unroll
    for (int i = 0; i < 8; ++i) {
        unsigned long long best = ~0ull;
#pragma unroll
        for (int j = 0; j < 8; ++j) {
            int c = c0 + tx + 16 * j;
            float score = fmaf(-2.f, acc[i][j], e2[c]);  // ||x||^2 dropped
            unsigned long long key =
                ((unsigned long long)fkey(score) << 32) | (unsigned int)c;
            if (key < best) best = key;
        }
        mykey[i] = best;
    }

    // reduce across the 16 tx sharing each row (reuse smem), then global merge
    unsigned long long* red = (unsigned long long*)smem;  // [128][16]
#pragma unroll
    for (int i = 0; i < 8; ++i) red[(ty + 16 * i) * 16 + tx] = mykey[i];
    __syncthreads();
    if (threadIdx.x < BM) {
        unsigned long long b = red[threadIdx.x * 16];
#pragma unroll
        for (int t = 1; t < 16; ++t) {
            unsigned long long v = red[threadIdx.x * 16 + t];
            if (v < b) b = v;
        }
        atomicMin(&packed[r0 + threadIdx.x], b);
    }
}

// ---- unpack packed (score,idx) -> ind_ws + ind_out ----
__global__ void unpack_kernel(const unsigned long long* __restrict__ packed,
                              int* __restrict__ ind_ws,
                              float* __restrict__ ind_out) {
    const int row = blockIdx.x * blockDim.x + threadIdx.x;
    int k = (int)(packed[row] & 0xFFFFFFFFull);
    ind_ws[row] = k;
    ind_out[row] = (float)k;
}

// ---- gather quantize + scatter stats (one wave = one row) ----
__global__ void scatter_kernel(const float* __restrict__ x,
                               const float* __restrict__ embed,
                               const int* __restrict__ ind,
                               float* __restrict__ quant,
                               float* __restrict__ cs,
                               float* __restrict__ es) {
    const int t = blockIdx.x * blockDim.x + threadIdx.x;  // over N*DIM
    const int row = t >> 6;
    const int d = t & 63;
    const int k = ind[row];                    // broadcast within wave
    quant[t] = embed[(size_t)k * DIM + d];     // coalesced gather
    atomicAdd(&es[(size_t)k * DIM + d], x[t]); // fp32 device-scope atomic
    if (d == 0) atomicAdd(&cs[k], 1.0f);       // one atomic per wave
}

extern "C" void kernel_launch(void* const* d_in, const int* in_sizes, int n_in,
                              void* d_out, int out_size, void* d_ws, size_t ws_size,
                              hipStream_t stream) {
    const float* x     = (const float*)d_in[0];
    const float* embed = (const float*)d_in[1];

    float* out     = (float*)d_out;
    float* quant   = out;                              // [N, D]
    float* ind_out = out + (size_t)N_ROWS * DIM;       // [N] (as float)
    float* cs      = ind_out + N_ROWS;                 // [K]
    float* es      = cs + K_CODES;                     // [K, D]

    // ws: e2 [K] | pad | packed [N] u64 | ind_ws [N]
    float* e2 = (float*)d_ws;
    unsigned long long* packed =
        (unsigned long long*)((char*)d_ws + 8192 * sizeof(float));  // 8B-aligned
    int* ind_ws = (int*)(packed + N_ROWS);

    hipMemsetAsync(cs, 0, (size_t)(K_CODES + K_CODES * DIM) * sizeof(float), stream);
    hipMemsetAsync(packed, 0xFF, (size_t)N_ROWS * 8, stream);  // u64 max

    e2_kernel<<<K_CODES / 256, 256, 0, stream>>>(embed, e2);
    dist_argmin_kernel<<<dim3(N_ROWS / BM, K_CODES / BN), 256, 0, stream>>>(
        x, embed, e2, packed);
    unpack_kernel<<<N_ROWS / 256, 256, 0, stream>>>(packed, ind_ws, ind_out);
    scatter_kernel<<<(size_t)N_ROWS * DIM / 256, 256, 0, stream>>>(
        x, embed, ind_ws, quant, cs, es);
}